// Round 1
// baseline (551.966 us; speedup 1.0000x reference)
//
#include <hip/hip_runtime.h>

#define BATCH 4096
#define DM 768
#define LTOT 10240
#define NG 124

typedef __bf16 bf16x8 __attribute__((ext_vector_type(8)));
typedef short short8 __attribute__((ext_vector_type(8)));
typedef float f32x4 __attribute__((ext_vector_type(4)));

struct Ptr5 { const float* p[5]; };

__device__ __forceinline__ unsigned short f2bf(float f) {
    unsigned u = __builtin_bit_cast(unsigned, f);
    unsigned r = (u + 0x7FFFu + ((u >> 16) & 1u)) >> 16;   // RNE
    return (unsigned short)r;
}

// ---------------- conversion kernels ----------------

__global__ __launch_bounds__(256) void conv_x_k(const float* __restrict__ x,
                                                unsigned short* __restrict__ xb) {
    int i = blockIdx.x * 256 + threadIdx.x;     // float4 index
    float4 v = ((const float4*)x)[i];
    ushort4 o;
    o.x = f2bf(v.x); o.y = f2bf(v.y); o.z = f2bf(v.z); o.w = f2bf(v.w);
    ((ushort4*)xb)[i] = o;
}

// V{g}: (n, r, 768) flat == rows of V_all for that group's l-range. Copy+cast,
// and accumulate per-n sum of squares (Frobenius) via LDS partials.
__global__ __launch_bounds__(256) void conv_v_k(Ptr5 vp, unsigned short* __restrict__ vb,
                                                float* __restrict__ vn2) {
    __shared__ float sh[64];
    int g = blockIdx.y;
    int i = blockIdx.x * 256 + threadIdx.x;     // float4 index, 0..393215
    int idx = i * 4;
    int r = 512 >> g;
    const float* src = vp.p[g];
    float4 v = ((const float4*)src)[i];
    ushort4 o;
    o.x = f2bf(v.x); o.y = f2bf(v.y); o.z = f2bf(v.z); o.w = f2bf(v.w);
    ((ushort4*)(vb + (size_t)(g << 11) * DM))[i] = o;
    float s = v.x*v.x + v.y*v.y + v.z*v.z + v.w*v.w;
    int nloc = idx / (r * DM);
    if (threadIdx.x < 64) sh[threadIdx.x] = 0.f;
    __syncthreads();
    atomicAdd(&sh[nloc], s);
    __syncthreads();
    const int basen[5] = {0, 4, 12, 28, 60};
    int ngc = 4 << g;
    if (threadIdx.x < ngc && sh[threadIdx.x] != 0.f)
        atomicAdd(&vn2[basen[g] + threadIdx.x], sh[threadIdx.x]);
}

// U{g}: (n, 768, r) -> W2T (768 x LTOT): W2T[d][gbase + n*r + rr] = U[n][d][rr]
__global__ __launch_bounds__(256) void conv_u_k(Ptr5 up, unsigned short* __restrict__ w2t,
                                                float* __restrict__ un2) {
    __shared__ float sh[64];
    int g = blockIdx.y;
    int i = blockIdx.x * 256 + threadIdx.x;
    int idx = i * 4;
    int r = 512 >> g;
    int lr = 9 - g;
    const float* src = up.p[g];
    float4 v = ((const float4*)src)[i];
    int rr = idx & (r - 1);
    int t2 = idx >> lr;            // n*768 + d
    int d  = t2 % DM;
    int n  = t2 / DM;
    ushort4 o;
    o.x = f2bf(v.x); o.y = f2bf(v.y); o.z = f2bf(v.z); o.w = f2bf(v.w);
    size_t dst = (size_t)d * LTOT + (size_t)(g << 11) + (size_t)n * r + rr;
    *(ushort4*)(w2t + dst) = o;
    float s = v.x*v.x + v.y*v.y + v.z*v.z + v.w*v.w;
    if (threadIdx.x < 64) sh[threadIdx.x] = 0.f;
    __syncthreads();
    atomicAdd(&sh[n], s);
    __syncthreads();
    const int basen[5] = {0, 4, 12, 28, 60};
    int ngc = 4 << g;
    if (threadIdx.x < ngc && sh[threadIdx.x] != 0.f)
        atomicAdd(&un2[basen[g] + threadIdx.x], sh[threadIdx.x]);
}

// ---------------- gate kernel (fp32-exact; gates are graded outputs) ----------------

__global__ __launch_bounds__(256) void gate_k(const float* __restrict__ x, Ptr5 ep, Ptr5 bp,
                                              float* __restrict__ gate_ws,
                                              float* __restrict__ outg,
                                              float* __restrict__ gate_sum,
                                              float* __restrict__ active) {
    __shared__ float4 xs[16][193];          // pad: stride 772 words -> 2-way (free)
    __shared__ float ssum[124];
    __shared__ unsigned scnt;
    int tid = threadIdx.x;
    if (tid < 124) ssum[tid] = 0.f;
    if (tid == 0) scnt = 0u;
    int b0 = blockIdx.x * 16;
    for (int i = tid; i < 16 * 192; i += 256) {
        int row = i / 192, c = i - row * 192;
        xs[row][c] = ((const float4*)(x + (size_t)(b0 + row) * DM))[c];
    }
    __syncthreads();
    unsigned cl = 0;
    for (int pp = tid; pp < 16 * NG; pp += 256) {
        int row = pp & 15, n = pp >> 4;
        int g = (n < 4) ? 0 : (n < 12) ? 1 : (n < 28) ? 2 : (n < 60) ? 3 : 4;
        const int basen[5] = {0, 4, 12, 28, 60};
        int ni = n - basen[g];
        const float* e = ep.p[g] + (size_t)ni * DM;
        float a0 = 0.f, a1 = 0.f, a2 = 0.f, a3 = 0.f;
        for (int k = 0; k < 192; k++) {
            float4 xv = xs[row][k];
            float4 ev = ((const float4*)e)[k];
            a0 = fmaf(xv.x, ev.x, a0);
            a1 = fmaf(xv.y, ev.y, a1);
            a2 = fmaf(xv.z, ev.z, a2);
            a3 = fmaf(xv.w, ev.w, a3);
        }
        float pre = (a0 + a1) + (a2 + a3) - bp.p[g][ni];
        float gt = pre > 0.f ? pre : 0.f;
        int grow = b0 + row;
        gate_ws[(size_t)grow * NG + n] = gt;
        const size_t baseg[5] = {3145730ull, 3145730ull + 16384, 3145730ull + 49152,
                                 3145730ull + 114688, 3145730ull + 245760};
        outg[baseg[g] + (size_t)grow * (4 << g) + ni] = gt;
        atomicAdd(&ssum[n], gt);
        if (pre > 0.f) cl++;
    }
    if (cl) atomicAdd(&scnt, cl);
    __syncthreads();
    if (tid < 124) { float s = ssum[tid]; if (s != 0.f) atomicAdd(&gate_sum[tid], s); }
    if (tid == 0 && scnt) atomicAdd(active, (float)scnt);
}

// ---------------- MFMA GEMM (NT: C = A @ B^T), 128x128 tile, BK=64 ----------------

__device__ __forceinline__ void stage128x64(const unsigned short* __restrict__ src, int ld,
                                            unsigned short* lds, int wave, int lane) {
    int colb = (lane & 7) * 8;
    int rowb = lane >> 3;
    #pragma unroll
    for (int i = 0; i < 4; i++) {
        int c = wave * 4 + i;                 // 1KB chunk = 8 rows of 64 bf16
        const unsigned short* gp = src + (size_t)(c * 8 + rowb) * ld + colb;
        __builtin_amdgcn_global_load_lds((const __attribute__((address_space(1))) void*)gp,
                                         (__attribute__((address_space(3))) void*)(lds + c * 512),
                                         16, 0, 0);
    }
}

// EPI=0: apply gate, store bf16 Hg.  EPI=1: atomicAdd fp32 into out (split-K).
template <int EPI>
__global__ __launch_bounds__(256) void gemm_nt(const unsigned short* __restrict__ A,
                                               const unsigned short* __restrict__ Bm,
                                               int Kblk, int lda, int ldb,
                                               void* __restrict__ Cout,
                                               const float* __restrict__ gate, int ldc) {
    __shared__ unsigned short lA[128 * 64];
    __shared__ unsigned short lB[128 * 64];
    int tid = threadIdx.x, wave = tid >> 6, lane = tid & 63;
    int m0 = blockIdx.y * 128, n0 = blockIdx.x * 128;
    A  += (size_t)m0 * lda + (size_t)blockIdx.z * Kblk;
    Bm += (size_t)n0 * ldb + (size_t)blockIdx.z * Kblk;
    f32x4 acc[4][4] = {};
    int wm = wave >> 1, wn = wave & 1;
    int lan15 = lane & 15, quad = lane >> 4;

    for (int k0 = 0; k0 < Kblk; k0 += 64) {
        stage128x64(A + k0, lda, lA, wave, lane);
        stage128x64(Bm + k0, ldb, lB, wave, lane);
        __syncthreads();
        #pragma unroll
        for (int kk = 0; kk < 2; kk++) {
            int kof = kk * 32 + quad * 8;
            bf16x8 af[4], bfr[4];
            #pragma unroll
            for (int t = 0; t < 4; t++) {
                short8 ra = *(const short8*)(lA + (size_t)(wm * 64 + t * 16 + lan15) * 64 + kof);
                short8 rb = *(const short8*)(lB + (size_t)(wn * 64 + t * 16 + lan15) * 64 + kof);
                af[t]  = __builtin_bit_cast(bf16x8, ra);
                bfr[t] = __builtin_bit_cast(bf16x8, rb);
            }
            #pragma unroll
            for (int mt = 0; mt < 4; mt++)
                #pragma unroll
                for (int nt = 0; nt < 4; nt++)
                    acc[mt][nt] = __builtin_amdgcn_mfma_f32_16x16x32_bf16(af[mt], bfr[nt],
                                                                          acc[mt][nt], 0, 0, 0);
        }
        __syncthreads();
    }

    const int basen[5] = {0, 4, 12, 28, 60};
    if (EPI == 0) {
        unsigned short* H = (unsigned short*)Cout;
        #pragma unroll
        for (int nt = 0; nt < 4; nt++) {
            int col = n0 + wn * 64 + nt * 16 + lan15;     // l index
            int g = col >> 11;
            int ngl = basen[g] + ((col & 2047) >> (9 - g));
            #pragma unroll
            for (int mt = 0; mt < 4; mt++) {
                int r0 = m0 + wm * 64 + mt * 16 + quad * 4;
                #pragma unroll
                for (int rg = 0; rg < 4; rg++) {
                    float gv = gate[(size_t)(r0 + rg) * NG + ngl];
                    H[(size_t)(r0 + rg) * ldc + col] = f2bf(acc[mt][nt][rg] * gv);
                }
            }
        }
    } else {
        float* O = (float*)Cout;
        #pragma unroll
        for (int nt = 0; nt < 4; nt++) {
            int col = n0 + wn * 64 + nt * 16 + lan15;
            #pragma unroll
            for (int mt = 0; mt < 4; mt++) {
                int r0 = m0 + wm * 64 + mt * 16 + quad * 4;
                #pragma unroll
                for (int rg = 0; rg < 4; rg++)
                    atomicAdd(&O[(size_t)(r0 + rg) * ldc + col], acc[mt][nt][rg]);
            }
        }
    }
}

// ---------------- stats ----------------

__global__ void stats_k(const float* __restrict__ st, float* __restrict__ o2) {
    // st: [0,124) gate_sum, [124,248) un2, [248,372) vn2, [372] active
    __shared__ float sh[128];
    int t = threadIdx.x;
    float v = 0.f;
    if (t < NG) {
        int g = (t < 4) ? 0 : (t < 12) ? 1 : (t < 28) ? 2 : (t < 60) ? 3 : 4;
        float rr = (float)(512 >> g);
        float mean = st[t] * (1.0f / BATCH);
        float frob = sqrtf(st[124 + t] * st[248 + t]) / sqrtf(768.0f * rr);
        v = tanhf(mean) * frob;
    }
    sh[t] = v;
    __syncthreads();
    for (int s = 64; s > 0; s >>= 1) { if (t < s) sh[t] += sh[t + s]; __syncthreads(); }
    if (t == 0) { o2[0] = sh[0]; o2[1] = st[372] * (1.0f / BATCH); }
}

// ---------------- launcher ----------------

extern "C" void kernel_launch(void* const* d_in, const int* in_sizes, int n_in,
                              void* d_out, int out_size, void* d_ws, size_t ws_size,
                              hipStream_t stream) {
    const float* x = (const float*)d_in[0];
    Ptr5 vp, up, ep, bp;
    for (int g = 0; g < 5; g++) {
        vp.p[g] = (const float*)d_in[1 + 4 * g];
        up.p[g] = (const float*)d_in[2 + 4 * g];
        ep.p[g] = (const float*)d_in[3 + 4 * g];
        bp.p[g] = (const float*)d_in[4 + 4 * g];
    }
    float* out = (float*)d_out;
    char* ws = (char*)d_ws;
    size_t off = 0;
    unsigned short* xb  = (unsigned short*)(ws + off); off += (size_t)BATCH * DM * 2;
    unsigned short* vb  = (unsigned short*)(ws + off); off += (size_t)LTOT * DM * 2;
    unsigned short* w2t = (unsigned short*)(ws + off); off += (size_t)LTOT * DM * 2;
    float* gate_ws      = (float*)(ws + off);          off += (size_t)BATCH * NG * 4;
    float* stats        = (float*)(ws + off);          off += 4096;
    unsigned short* Hg  = (unsigned short*)(ws + off);
    size_t fixed = off;
    int CB = BATCH;
    while (CB > 128 && fixed + (size_t)CB * LTOT * 2 > ws_size) CB >>= 1;

    hipMemsetAsync(stats, 0, 4096, stream);
    hipMemsetAsync(d_out, 0, (size_t)BATCH * DM * 4, stream);   // atomic target

    conv_x_k<<<dim3(BATCH * DM / 4 / 256), 256, 0, stream>>>(x, xb);
    conv_v_k<<<dim3(1536, 5), 256, 0, stream>>>(vp, vb, stats + 248);
    conv_u_k<<<dim3(1536, 5), 256, 0, stream>>>(up, w2t, stats + 124);
    gate_k<<<dim3(BATCH / 16), 256, 0, stream>>>(x, ep, bp, gate_ws, out, stats, stats + 372);

    int nch = BATCH / CB;
    for (int c = 0; c < nch; c++) {
        gemm_nt<0><<<dim3(LTOT / 128, CB / 128, 1), 256, 0, stream>>>(
            xb + (size_t)c * CB * DM, vb, DM, DM, DM,
            (void*)Hg, gate_ws + (size_t)c * CB * NG, LTOT);
        gemm_nt<1><<<dim3(DM / 128, CB / 128, 4), 256, 0, stream>>>(
            Hg, w2t, LTOT / 4, LTOT, LTOT,
            (void*)(out + (size_t)c * CB * DM), nullptr, DM);
    }
    stats_k<<<1, 128, 0, stream>>>(stats, out + (size_t)BATCH * DM);
}

// Round 2
// 513.590 us; speedup vs baseline: 1.0747x; 1.0747x over previous
//
#include <hip/hip_runtime.h>

#define BATCH 4096
#define DM 768
#define LTOT 10240
#define NG 124

typedef __bf16 bf16x8 __attribute__((ext_vector_type(8)));
typedef short short8 __attribute__((ext_vector_type(8)));
typedef float f32x4 __attribute__((ext_vector_type(4)));

struct Ptr5 { const float* p[5]; };

__device__ __forceinline__ unsigned short f2bf(float f) {
    unsigned u = __builtin_bit_cast(unsigned, f);
    unsigned r = (u + 0x7FFFu + ((u >> 16) & 1u)) >> 16;   // RNE
    return (unsigned short)r;
}

// ---------------- conversion kernels ----------------

// V{g}: (n, r, 768) flat == rows of V_all for that group's l-range. Copy+cast,
// and accumulate per-n sum of squares (Frobenius) via LDS partials.
__global__ __launch_bounds__(256) void conv_v_k(Ptr5 vp, unsigned short* __restrict__ vb,
                                                float* __restrict__ vn2) {
    __shared__ float sh[64];
    int g = blockIdx.y;
    int i = blockIdx.x * 256 + threadIdx.x;     // float4 index, 0..393215
    int idx = i * 4;
    int r = 512 >> g;
    const float* src = vp.p[g];
    float4 v = ((const float4*)src)[i];
    ushort4 o;
    o.x = f2bf(v.x); o.y = f2bf(v.y); o.z = f2bf(v.z); o.w = f2bf(v.w);
    ((ushort4*)(vb + (size_t)(g << 11) * DM))[i] = o;
    float s = v.x*v.x + v.y*v.y + v.z*v.z + v.w*v.w;
    int nloc = idx / (r * DM);
    if (threadIdx.x < 64) sh[threadIdx.x] = 0.f;
    __syncthreads();
    atomicAdd(&sh[nloc], s);
    __syncthreads();
    const int basen[5] = {0, 4, 12, 28, 60};
    int ngc = 4 << g;
    if (threadIdx.x < ngc && sh[threadIdx.x] != 0.f)
        atomicAdd(&vn2[basen[g] + threadIdx.x], sh[threadIdx.x]);
}

// U{g}: (n, 768, r) -> W2T (768 x LTOT): W2T[d][gbase + n*r + rr] = U[n][d][rr]
__global__ __launch_bounds__(256) void conv_u_k(Ptr5 up, unsigned short* __restrict__ w2t,
                                                float* __restrict__ un2) {
    __shared__ float sh[64];
    int g = blockIdx.y;
    int i = blockIdx.x * 256 + threadIdx.x;
    int idx = i * 4;
    int r = 512 >> g;
    int lr = 9 - g;
    const float* src = up.p[g];
    float4 v = ((const float4*)src)[i];
    int rr = idx & (r - 1);
    int t2 = idx >> lr;            // n*768 + d
    int d  = t2 % DM;
    int n  = t2 / DM;
    ushort4 o;
    o.x = f2bf(v.x); o.y = f2bf(v.y); o.z = f2bf(v.z); o.w = f2bf(v.w);
    size_t dst = (size_t)d * LTOT + (size_t)(g << 11) + (size_t)n * r + rr;
    *(ushort4*)(w2t + dst) = o;
    float s = v.x*v.x + v.y*v.y + v.z*v.z + v.w*v.w;
    if (threadIdx.x < 64) sh[threadIdx.x] = 0.f;
    __syncthreads();
    atomicAdd(&sh[n], s);
    __syncthreads();
    const int basen[5] = {0, 4, 12, 28, 60};
    int ngc = 4 << g;
    if (threadIdx.x < ngc && sh[threadIdx.x] != 0.f)
        atomicAdd(&un2[basen[g] + threadIdx.x], sh[threadIdx.x]);
}

// ---------------- gate kernel (fp32-exact; gates are graded outputs) ----------------
// Also emits xb (bf16 cast of x) since x is already staged in LDS here.

__global__ __launch_bounds__(256) void gate_k(const float* __restrict__ x, Ptr5 ep, Ptr5 bp,
                                              float* __restrict__ gate_ws,
                                              unsigned short* __restrict__ xb,
                                              float* __restrict__ outg,
                                              float* __restrict__ gate_sum,
                                              float* __restrict__ active) {
    __shared__ float4 xs[16][193];          // pad: stride 772 words -> 2-way (free)
    __shared__ float ssum[124];
    __shared__ unsigned scnt;
    int tid = threadIdx.x;
    if (tid < 124) ssum[tid] = 0.f;
    if (tid == 0) scnt = 0u;
    int b0 = blockIdx.x * 16;
    for (int i = tid; i < 16 * 192; i += 256) {
        int row = i / 192, c = i - row * 192;
        float4 v = ((const float4*)(x + (size_t)(b0 + row) * DM))[c];
        xs[row][c] = v;
        ushort4 o;
        o.x = f2bf(v.x); o.y = f2bf(v.y); o.z = f2bf(v.z); o.w = f2bf(v.w);
        ((ushort4*)xb)[(size_t)(b0 + row) * 192 + c] = o;
    }
    __syncthreads();
    unsigned cl = 0;
    for (int pp = tid; pp < 16 * NG; pp += 256) {
        int row = pp & 15, n = pp >> 4;
        int g = (n < 4) ? 0 : (n < 12) ? 1 : (n < 28) ? 2 : (n < 60) ? 3 : 4;
        const int basen[5] = {0, 4, 12, 28, 60};
        int ni = n - basen[g];
        const float* e = ep.p[g] + (size_t)ni * DM;
        float a0 = 0.f, a1 = 0.f, a2 = 0.f, a3 = 0.f;
        for (int k = 0; k < 192; k++) {
            float4 xv = xs[row][k];
            float4 ev = ((const float4*)e)[k];
            a0 = fmaf(xv.x, ev.x, a0);
            a1 = fmaf(xv.y, ev.y, a1);
            a2 = fmaf(xv.z, ev.z, a2);
            a3 = fmaf(xv.w, ev.w, a3);
        }
        float pre = (a0 + a1) + (a2 + a3) - bp.p[g][ni];
        float gt = pre > 0.f ? pre : 0.f;
        int grow = b0 + row;
        gate_ws[(size_t)grow * NG + n] = gt;
        const size_t baseg[5] = {3145730ull, 3145730ull + 16384, 3145730ull + 49152,
                                 3145730ull + 114688, 3145730ull + 245760};
        outg[baseg[g] + (size_t)grow * (4 << g) + ni] = gt;
        atomicAdd(&ssum[n], gt);
        if (pre > 0.f) cl++;
    }
    if (cl) atomicAdd(&scnt, cl);
    __syncthreads();
    if (tid < 124) { float s = ssum[tid]; if (s != 0.f) atomicAdd(&gate_sum[tid], s); }
    if (tid == 0 && scnt) atomicAdd(active, (float)scnt);
}

// ---------------- MFMA GEMM (NT: C = A @ B^T) ----------------
// ROWSx64 bf16 tile staged via async global->LDS, 16B/lane.
template <int ROWS, int NT>
__device__ __forceinline__ void stage(const unsigned short* __restrict__ src, int ld,
                                      unsigned short* lds, int wv, int lane) {
    int colb = (lane & 7) * 8;
    int rsub = lane >> 3;
    #pragma unroll
    for (int i = 0; i < ROWS * 8 / NT; i++) {
        int c = i * (NT / 64) + wv;           // 512-elem chunk = 8 rows of 64 bf16
        const unsigned short* gp = src + (size_t)(c * 8 + rsub) * ld + colb;
        __builtin_amdgcn_global_load_lds((const __attribute__((address_space(1))) void*)gp,
                                         (__attribute__((address_space(3))) void*)(lds + c * 512),
                                         16, 0, 0);
    }
}

// EPI=0: apply gate, store bf16 Hg.  EPI=1: plain fp32 store into split-K partials.
template <int BM, int BN, int EPI, int NT>
__global__ __launch_bounds__(NT) void gemm_nt(const unsigned short* __restrict__ A,
                                              const unsigned short* __restrict__ Bm,
                                              int Kblk, int lda, int ldb,
                                              void* __restrict__ Cout,
                                              const float* __restrict__ gate, int ldc) {
    __shared__ unsigned short lA[BM * 64];
    __shared__ unsigned short lB[BN * 64];
    int tid = threadIdx.x, wave = tid >> 6, lane = tid & 63;
    constexpr int WN = BN / 64;
    int wm = wave / WN, wn = wave % WN;
    int m0 = blockIdx.x * BM, n0 = blockIdx.y * BN;    // m is the FAST grid dim
    A  += (size_t)m0 * lda + (size_t)blockIdx.z * Kblk;
    Bm += (size_t)n0 * ldb + (size_t)blockIdx.z * Kblk;
    f32x4 acc[4][4] = {};
    int lan15 = lane & 15, quad = lane >> 4;

    for (int k0 = 0; k0 < Kblk; k0 += 64) {
        stage<BM, NT>(A + k0, lda, lA, wave, lane);
        stage<BN, NT>(Bm + k0, ldb, lB, wave, lane);
        __syncthreads();
        #pragma unroll
        for (int kk = 0; kk < 2; kk++) {
            int kof = kk * 32 + quad * 8;
            bf16x8 af[4], bfr[4];
            #pragma unroll
            for (int t = 0; t < 4; t++) {
                short8 ra = *(const short8*)(lA + (size_t)(wm * 64 + t * 16 + lan15) * 64 + kof);
                short8 rb = *(const short8*)(lB + (size_t)(wn * 64 + t * 16 + lan15) * 64 + kof);
                af[t]  = __builtin_bit_cast(bf16x8, ra);
                bfr[t] = __builtin_bit_cast(bf16x8, rb);
            }
            #pragma unroll
            for (int mt = 0; mt < 4; mt++)
                #pragma unroll
                for (int nt = 0; nt < 4; nt++)
                    acc[mt][nt] = __builtin_amdgcn_mfma_f32_16x16x32_bf16(af[mt], bfr[nt],
                                                                          acc[mt][nt], 0, 0, 0);
        }
        __syncthreads();
    }

    const int basen[5] = {0, 4, 12, 28, 60};
    if (EPI == 0) {
        unsigned short* H = (unsigned short*)Cout;
        #pragma unroll
        for (int nt = 0; nt < 4; nt++) {
            int col = n0 + wn * 64 + nt * 16 + lan15;     // l index
            int g = col >> 11;
            int ngl = basen[g] + ((col & 2047) >> (9 - g));
            #pragma unroll
            for (int mt = 0; mt < 4; mt++) {
                int r0 = m0 + wm * 64 + mt * 16 + quad * 4;
                #pragma unroll
                for (int rg = 0; rg < 4; rg++) {
                    float gv = gate[(size_t)(r0 + rg) * NG + ngl];
                    H[(size_t)(r0 + rg) * ldc + col] = f2bf(acc[mt][nt][rg] * gv);
                }
            }
        }
    } else {
        float* P = (float*)Cout;
        P += (size_t)blockIdx.z * gridDim.x * BM * ldc;   // partial buffer for this z
        #pragma unroll
        for (int nt = 0; nt < 4; nt++) {
            int col = n0 + wn * 64 + nt * 16 + lan15;
            #pragma unroll
            for (int mt = 0; mt < 4; mt++) {
                int r0 = m0 + wm * 64 + mt * 16 + quad * 4;
                #pragma unroll
                for (int rg = 0; rg < 4; rg++)
                    P[(size_t)(r0 + rg) * ldc + col] = acc[mt][nt][rg];
            }
        }
    }
}

// ---------------- split-K reduce ----------------

__global__ __launch_bounds__(256) void reduce_k(const float4* __restrict__ P,
                                                float4* __restrict__ out, int quarter) {
    int i = blockIdx.x * 256 + threadIdx.x;
    float4 a = P[i], b = P[i + quarter], c = P[i + 2 * quarter], d = P[i + 3 * quarter];
    float4 o;
    o.x = (a.x + b.x) + (c.x + d.x);
    o.y = (a.y + b.y) + (c.y + d.y);
    o.z = (a.z + b.z) + (c.z + d.z);
    o.w = (a.w + b.w) + (c.w + d.w);
    out[i] = o;
}

// ---------------- stats ----------------

__global__ void stats_k(const float* __restrict__ st, float* __restrict__ o2) {
    // st: [0,124) gate_sum, [124,248) un2, [248,372) vn2, [372] active
    __shared__ float sh[128];
    int t = threadIdx.x;
    float v = 0.f;
    if (t < NG) {
        int g = (t < 4) ? 0 : (t < 12) ? 1 : (t < 28) ? 2 : (t < 60) ? 3 : 4;
        float rr = (float)(512 >> g);
        float mean = st[t] * (1.0f / BATCH);
        float frob = sqrtf(st[124 + t] * st[248 + t]) / sqrtf(768.0f * rr);
        v = tanhf(mean) * frob;
    }
    sh[t] = v;
    __syncthreads();
    for (int s = 64; s > 0; s >>= 1) { if (t < s) sh[t] += sh[t + s]; __syncthreads(); }
    if (t == 0) { o2[0] = sh[0]; o2[1] = st[372] * (1.0f / BATCH); }
}

// ---------------- launcher ----------------

extern "C" void kernel_launch(void* const* d_in, const int* in_sizes, int n_in,
                              void* d_out, int out_size, void* d_ws, size_t ws_size,
                              hipStream_t stream) {
    const float* x = (const float*)d_in[0];
    Ptr5 vp, up, ep, bp;
    for (int g = 0; g < 5; g++) {
        vp.p[g] = (const float*)d_in[1 + 4 * g];
        up.p[g] = (const float*)d_in[2 + 4 * g];
        ep.p[g] = (const float*)d_in[3 + 4 * g];
        bp.p[g] = (const float*)d_in[4 + 4 * g];
    }
    float* out = (float*)d_out;
    char* ws = (char*)d_ws;
    size_t off = 0;
    unsigned short* xb  = (unsigned short*)(ws + off); off += (size_t)BATCH * DM * 2;
    unsigned short* vb  = (unsigned short*)(ws + off); off += (size_t)LTOT * DM * 2;
    unsigned short* w2t = (unsigned short*)(ws + off); off += (size_t)LTOT * DM * 2;
    float* gate_ws      = (float*)(ws + off);          off += (size_t)BATCH * NG * 4;
    float* stats        = (float*)(ws + off);          off += 4096;
    size_t fixed = off;
    int CB = BATCH;
    while (CB > 128 && fixed + (size_t)CB * LTOT * 2 + 4ull * CB * DM * 4 > ws_size) CB >>= 1;
    unsigned short* Hg  = (unsigned short*)(ws + fixed);
    float* partial      = (float*)(ws + fixed + (size_t)CB * LTOT * 2);

    hipMemsetAsync(stats, 0, 4096, stream);

    conv_v_k<<<dim3(1536, 5), 256, 0, stream>>>(vp, vb, stats + 248);
    conv_u_k<<<dim3(1536, 5), 256, 0, stream>>>(up, w2t, stats + 124);
    gate_k<<<dim3(BATCH / 16), 256, 0, stream>>>(x, ep, bp, gate_ws, xb, out, stats, stats + 372);

    int nch = BATCH / CB;
    for (int c = 0; c < nch; c++) {
        // GEMM1: Hg = gate .* (x @ V^T)   (M=CB, N=10240, K=768), m-fast grid
        gemm_nt<128, 256, 0, 512><<<dim3(CB / 128, LTOT / 256, 1), 512, 0, stream>>>(
            xb + (size_t)c * CB * DM, vb, DM, DM, DM,
            (void*)Hg, gate_ws + (size_t)c * CB * NG, LTOT);
        // GEMM2: out = Hg @ W2   (M=CB, N=768, K=10240), split-K=4 into partials
        gemm_nt<128, 128, 1, 256><<<dim3(CB / 128, DM / 128, 4), 256, 0, stream>>>(
            Hg, w2t, LTOT / 4, LTOT, LTOT,
            (void*)partial, nullptr, DM);
        reduce_k<<<dim3(CB * 192 / 256), 256, 0, stream>>>(
            (const float4*)partial, (float4*)(out + (size_t)c * CB * DM), CB * DM / 4);
    }
    stats_k<<<1, 128, 0, stream>>>(stats, out + (size_t)BATCH * DM);
}

// Round 3
// 465.175 us; speedup vs baseline: 1.1866x; 1.1041x over previous
//
#include <hip/hip_runtime.h>

#define BATCH 4096
#define DM 768
#define LTOT 10240
#define NG 124

typedef __bf16 bf16x8 __attribute__((ext_vector_type(8)));
typedef short short8 __attribute__((ext_vector_type(8)));
typedef float f32x4 __attribute__((ext_vector_type(4)));

struct Ptr5 { const float* p[5]; };

__device__ __forceinline__ unsigned short f2bf(float f) {
    unsigned u = __builtin_bit_cast(unsigned, f);
    unsigned r = (u + 0x7FFFu + ((u >> 16) & 1u)) >> 16;   // RNE
    return (unsigned short)r;
}

// ---------------- conversion kernels ----------------

// V{g}: (n, r, 768) flat == rows of V_all for that group's l-range. Copy+cast,
// and accumulate per-n sum of squares (Frobenius) via LDS partials.
__global__ __launch_bounds__(256) void conv_v_k(Ptr5 vp, unsigned short* __restrict__ vb,
                                                float* __restrict__ vn2) {
    __shared__ float sh[64];
    int g = blockIdx.y;
    int i = blockIdx.x * 256 + threadIdx.x;     // float4 index, 0..393215
    int idx = i * 4;
    int r = 512 >> g;
    const float* src = vp.p[g];
    float4 v = ((const float4*)src)[i];
    ushort4 o;
    o.x = f2bf(v.x); o.y = f2bf(v.y); o.z = f2bf(v.z); o.w = f2bf(v.w);
    ((ushort4*)(vb + (size_t)(g << 11) * DM))[i] = o;
    float s = v.x*v.x + v.y*v.y + v.z*v.z + v.w*v.w;
    int nloc = idx / (r * DM);
    if (threadIdx.x < 64) sh[threadIdx.x] = 0.f;
    __syncthreads();
    atomicAdd(&sh[nloc], s);
    __syncthreads();
    const int basen[5] = {0, 4, 12, 28, 60};
    int ngc = 4 << g;
    if (threadIdx.x < ngc && sh[threadIdx.x] != 0.f)
        atomicAdd(&vn2[basen[g] + threadIdx.x], sh[threadIdx.x]);
}

// U{g}: (n, 768, r) -> W2T (768 x LTOT): W2T[d][gbase + n*r + rr] = U[n][d][rr]
__global__ __launch_bounds__(256) void conv_u_k(Ptr5 up, unsigned short* __restrict__ w2t,
                                                float* __restrict__ un2) {
    __shared__ float sh[64];
    int g = blockIdx.y;
    int i = blockIdx.x * 256 + threadIdx.x;
    int idx = i * 4;
    int r = 512 >> g;
    int lr = 9 - g;
    const float* src = up.p[g];
    float4 v = ((const float4*)src)[i];
    int rr = idx & (r - 1);
    int t2 = idx >> lr;            // n*768 + d
    int d  = t2 % DM;
    int n  = t2 / DM;
    ushort4 o;
    o.x = f2bf(v.x); o.y = f2bf(v.y); o.z = f2bf(v.z); o.w = f2bf(v.w);
    size_t dst = (size_t)d * LTOT + (size_t)(g << 11) + (size_t)n * r + rr;
    *(ushort4*)(w2t + dst) = o;
    float s = v.x*v.x + v.y*v.y + v.z*v.z + v.w*v.w;
    if (threadIdx.x < 64) sh[threadIdx.x] = 0.f;
    __syncthreads();
    atomicAdd(&sh[n], s);
    __syncthreads();
    const int basen[5] = {0, 4, 12, 28, 60};
    int ngc = 4 << g;
    if (threadIdx.x < ngc && sh[threadIdx.x] != 0.f)
        atomicAdd(&un2[basen[g] + threadIdx.x], sh[threadIdx.x]);
}

// ---------------- gate kernel (fp32-exact; gates are graded outputs) ----------------
// Also emits xb (bf16 cast of x) since x is already staged in LDS here.

__global__ __launch_bounds__(256) void gate_k(const float* __restrict__ x, Ptr5 ep, Ptr5 bp,
                                              float* __restrict__ gate_ws,
                                              unsigned short* __restrict__ xb,
                                              float* __restrict__ outg,
                                              float* __restrict__ gate_sum,
                                              float* __restrict__ active) {
    __shared__ float4 xs[16][193];          // pad: stride 772 words -> 2-way (free)
    __shared__ float ssum[124];
    __shared__ unsigned scnt;
    int tid = threadIdx.x;
    if (tid < 124) ssum[tid] = 0.f;
    if (tid == 0) scnt = 0u;
    int b0 = blockIdx.x * 16;
    for (int i = tid; i < 16 * 192; i += 256) {
        int row = i / 192, c = i - row * 192;
        float4 v = ((const float4*)(x + (size_t)(b0 + row) * DM))[c];
        xs[row][c] = v;
        ushort4 o;
        o.x = f2bf(v.x); o.y = f2bf(v.y); o.z = f2bf(v.z); o.w = f2bf(v.w);
        ((ushort4*)xb)[(size_t)(b0 + row) * 192 + c] = o;
    }
    __syncthreads();
    unsigned cl = 0;
    for (int pp = tid; pp < 16 * NG; pp += 256) {
        int row = pp & 15, n = pp >> 4;
        int g = (n < 4) ? 0 : (n < 12) ? 1 : (n < 28) ? 2 : (n < 60) ? 3 : 4;
        const int basen[5] = {0, 4, 12, 28, 60};
        int ni = n - basen[g];
        const float* e = ep.p[g] + (size_t)ni * DM;
        float a0 = 0.f, a1 = 0.f, a2 = 0.f, a3 = 0.f;
        for (int k = 0; k < 192; k++) {
            float4 xv = xs[row][k];
            float4 ev = ((const float4*)e)[k];
            a0 = fmaf(xv.x, ev.x, a0);
            a1 = fmaf(xv.y, ev.y, a1);
            a2 = fmaf(xv.z, ev.z, a2);
            a3 = fmaf(xv.w, ev.w, a3);
        }
        float pre = (a0 + a1) + (a2 + a3) - bp.p[g][ni];
        float gt = pre > 0.f ? pre : 0.f;
        int grow = b0 + row;
        gate_ws[(size_t)grow * NG + n] = gt;
        const size_t baseg[5] = {3145730ull, 3145730ull + 16384, 3145730ull + 49152,
                                 3145730ull + 114688, 3145730ull + 245760};
        outg[baseg[g] + (size_t)grow * (4 << g) + ni] = gt;
        atomicAdd(&ssum[n], gt);
        if (pre > 0.f) cl++;
    }
    if (cl) atomicAdd(&scnt, cl);
    __syncthreads();
    if (tid < 124) { float s = ssum[tid]; if (s != 0.f) atomicAdd(&gate_sum[tid], s); }
    if (tid == 0 && scnt) atomicAdd(active, (float)scnt);
}

// ---------------- MFMA GEMM (NT: C = A @ B^T) ----------------
// ROWSx64 bf16 tile staged via async global->LDS, 16B/lane.
// XOR swizzle: physical granule (row, kb^(row&7)) holds logical (row, kb).
// global_load_lds puts lane L at chunk + L*16B; we permute the SOURCE column
// granule so reads at fixed logical kb fan out across all 8 bank groups.
template <int ROWS, int NT>
__device__ __forceinline__ void stage(const unsigned short* __restrict__ src, int ld,
                                      unsigned short* lds, int wv, int lane) {
    int rsub = lane >> 3;                      // 0..7: row within 8-row chunk
    int colb = ((lane ^ rsub) & 7) * 8;        // swizzled source granule
    #pragma unroll
    for (int i = 0; i < ROWS * 8 / NT; i++) {
        int c = i * (NT / 64) + wv;            // 512-elem chunk = 8 rows of 64 bf16
        const unsigned short* gp = src + (size_t)(c * 8 + rsub) * ld + colb;
        __builtin_amdgcn_global_load_lds((const __attribute__((address_space(1))) void*)gp,
                                         (__attribute__((address_space(3))) void*)(lds + c * 512),
                                         16, 0, 0);
    }
}

// EPI=0: apply gate, store bf16 Hg.  EPI=1: plain fp32 store into split-K partials.
template <int BM, int BN, int EPI, int NT>
__global__ __launch_bounds__(NT) void gemm_nt(const unsigned short* __restrict__ A,
                                              const unsigned short* __restrict__ Bm,
                                              int Kblk, int lda, int ldb,
                                              void* __restrict__ Cout,
                                              const float* __restrict__ gate, int ldc) {
    __shared__ unsigned short lA[BM * 64];
    __shared__ unsigned short lB[BN * 64];
    int tid = threadIdx.x, wave = tid >> 6, lane = tid & 63;
    constexpr int WN = BN / 64;
    int wm = wave / WN, wn = wave % WN;
    int m0 = blockIdx.x * BM, n0 = blockIdx.y * BN;    // m is the FAST grid dim
    A  += (size_t)m0 * lda + (size_t)blockIdx.z * Kblk;
    Bm += (size_t)n0 * ldb + (size_t)blockIdx.z * Kblk;
    f32x4 acc[4][4] = {};
    int lan15 = lane & 15, quad = lane >> 4;
    int sw = lan15 & 7;                         // row&7 for all fragment rows

    for (int k0 = 0; k0 < Kblk; k0 += 64) {
        stage<BM, NT>(A + k0, lda, lA, wave, lane);
        stage<BN, NT>(Bm + k0, ldb, lB, wave, lane);
        __syncthreads();
        #pragma unroll
        for (int kk = 0; kk < 2; kk++) {
            int kb = kk * 4 + quad;             // logical 16B granule in K
            int kel = (kb ^ sw) * 8;            // swizzled element offset
            bf16x8 af[4], bfr[4];
            #pragma unroll
            for (int t = 0; t < 4; t++) {
                short8 ra = *(const short8*)(lA + (size_t)(wm * 64 + t * 16 + lan15) * 64 + kel);
                short8 rb = *(const short8*)(lB + (size_t)(wn * 64 + t * 16 + lan15) * 64 + kel);
                af[t]  = __builtin_bit_cast(bf16x8, ra);
                bfr[t] = __builtin_bit_cast(bf16x8, rb);
            }
            #pragma unroll
            for (int mt = 0; mt < 4; mt++)
                #pragma unroll
                for (int nt = 0; nt < 4; nt++)
                    acc[mt][nt] = __builtin_amdgcn_mfma_f32_16x16x32_bf16(af[mt], bfr[nt],
                                                                          acc[mt][nt], 0, 0, 0);
        }
        __syncthreads();
    }

    const int basen[5] = {0, 4, 12, 28, 60};
    if (EPI == 0) {
        unsigned short* H = (unsigned short*)Cout;
        #pragma unroll
        for (int nt = 0; nt < 4; nt++) {
            int col = n0 + wn * 64 + nt * 16 + lan15;     // l index
            int g = col >> 11;
            int ngl = basen[g] + ((col & 2047) >> (9 - g));
            #pragma unroll
            for (int mt = 0; mt < 4; mt++) {
                int r0 = m0 + wm * 64 + mt * 16 + quad * 4;
                #pragma unroll
                for (int rg = 0; rg < 4; rg++) {
                    float gv = gate[(size_t)(r0 + rg) * NG + ngl];
                    H[(size_t)(r0 + rg) * ldc + col] = f2bf(acc[mt][nt][rg] * gv);
                }
            }
        }
    } else {
        float* P = (float*)Cout;
        P += (size_t)blockIdx.z * gridDim.x * BM * ldc;   // partial buffer for this z
        #pragma unroll
        for (int nt = 0; nt < 4; nt++) {
            int col = n0 + wn * 64 + nt * 16 + lan15;
            #pragma unroll
            for (int mt = 0; mt < 4; mt++) {
                int r0 = m0 + wm * 64 + mt * 16 + quad * 4;
                #pragma unroll
                for (int rg = 0; rg < 4; rg++)
                    P[(size_t)(r0 + rg) * ldc + col] = acc[mt][nt][rg];
            }
        }
    }
}

// ---------------- split-K reduce ----------------

__global__ __launch_bounds__(256) void reduce_k(const float4* __restrict__ P,
                                                float4* __restrict__ out, int quarter) {
    int i = blockIdx.x * 256 + threadIdx.x;
    float4 a = P[i], b = P[i + quarter], c = P[i + 2 * quarter], d = P[i + 3 * quarter];
    float4 o;
    o.x = (a.x + b.x) + (c.x + d.x);
    o.y = (a.y + b.y) + (c.y + d.y);
    o.z = (a.z + b.z) + (c.z + d.z);
    o.w = (a.w + b.w) + (c.w + d.w);
    out[i] = o;
}

// ---------------- stats ----------------

__global__ void stats_k(const float* __restrict__ st, float* __restrict__ o2) {
    // st: [0,124) gate_sum, [124,248) un2, [248,372) vn2, [372] active
    __shared__ float sh[128];
    int t = threadIdx.x;
    float v = 0.f;
    if (t < NG) {
        int g = (t < 4) ? 0 : (t < 12) ? 1 : (t < 28) ? 2 : (t < 60) ? 3 : 4;
        float rr = (float)(512 >> g);
        float mean = st[t] * (1.0f / BATCH);
        float frob = sqrtf(st[124 + t] * st[248 + t]) / sqrtf(768.0f * rr);
        v = tanhf(mean) * frob;
    }
    sh[t] = v;
    __syncthreads();
    for (int s = 64; s > 0; s >>= 1) { if (t < s) sh[t] += sh[t + s]; __syncthreads(); }
    if (t == 0) { o2[0] = sh[0]; o2[1] = st[372] * (1.0f / BATCH); }
}

// ---------------- launcher ----------------

extern "C" void kernel_launch(void* const* d_in, const int* in_sizes, int n_in,
                              void* d_out, int out_size, void* d_ws, size_t ws_size,
                              hipStream_t stream) {
    const float* x = (const float*)d_in[0];
    Ptr5 vp, up, ep, bp;
    for (int g = 0; g < 5; g++) {
        vp.p[g] = (const float*)d_in[1 + 4 * g];
        up.p[g] = (const float*)d_in[2 + 4 * g];
        ep.p[g] = (const float*)d_in[3 + 4 * g];
        bp.p[g] = (const float*)d_in[4 + 4 * g];
    }
    float* out = (float*)d_out;
    char* ws = (char*)d_ws;
    size_t off = 0;
    unsigned short* xb  = (unsigned short*)(ws + off); off += (size_t)BATCH * DM * 2;
    unsigned short* vb  = (unsigned short*)(ws + off); off += (size_t)LTOT * DM * 2;
    unsigned short* w2t = (unsigned short*)(ws + off); off += (size_t)LTOT * DM * 2;
    float* gate_ws      = (float*)(ws + off);          off += (size_t)BATCH * NG * 4;
    float* stats        = (float*)(ws + off);          off += 4096;
    size_t fixed = off;
    int CB = BATCH;
    while (CB > 128 && fixed + (size_t)CB * LTOT * 2 + 4ull * CB * DM * 4 > ws_size) CB >>= 1;
    unsigned short* Hg  = (unsigned short*)(ws + fixed);
    float* partial      = (float*)(ws + fixed + (size_t)CB * LTOT * 2);

    hipMemsetAsync(stats, 0, 4096, stream);

    conv_v_k<<<dim3(1536, 5), 256, 0, stream>>>(vp, vb, stats + 248);
    conv_u_k<<<dim3(1536, 5), 256, 0, stream>>>(up, w2t, stats + 124);
    gate_k<<<dim3(BATCH / 16), 256, 0, stream>>>(x, ep, bp, gate_ws, xb, out, stats, stats + 372);

    int nch = BATCH / CB;
    for (int c = 0; c < nch; c++) {
        // GEMM1: Hg = gate .* (x @ V^T)   (M=CB, N=10240, K=768), m-fast grid
        gemm_nt<128, 256, 0, 512><<<dim3(CB / 128, LTOT / 256, 1), 512, 0, stream>>>(
            xb + (size_t)c * CB * DM, vb, DM, DM, DM,
            (void*)Hg, gate_ws + (size_t)c * CB * NG, LTOT);
        // GEMM2: out = Hg @ W2   (M=CB, N=768, K=10240), split-K=4 into partials
        gemm_nt<128, 128, 1, 256><<<dim3(CB / 128, DM / 128, 4), 256, 0, stream>>>(
            Hg, w2t, LTOT / 4, LTOT, LTOT,
            (void*)partial, nullptr, DM);
        reduce_k<<<dim3(CB * 192 / 256), 256, 0, stream>>>(
            (const float4*)partial, (float4*)(out + (size_t)c * CB * DM), CB * DM / 4);
    }
    stats_k<<<1, 128, 0, stream>>>(stats, out + (size_t)BATCH * DM);
}